// Round 5
// baseline (117.408 us; speedup 1.0000x reference)
//
#include <hip/hip_runtime.h>
#include <math.h>

#define B_    16
#define D_    512
#define T_    4096
#define CBN_  1024
#define CD_   8
#define NTOK_ (B_ * T_)   // 65536

// ws layout (float offsets)
#define WS_WIN_T   0                        // [512][8]  w_in transposed: [i][o]
#define WS_CBN     4096                     // [1024][8] normalized codebook
#define WS_CQ      12288                    // [1024][4] cc=|cb_n|^2, ||q||, ||q||^2, pad
#define WS_PCB     16384                    // [1024][512] w_out @ cb^T + b_out
#define WS_ZEP     540672                   // [8][65536][8] z_e partials (chunk-major)
#define WS_IDX     4734976                  // int[65536]
#define WS_BPART   4800512                  // float[1024] loss partials

#define OUT_OFF_LOSS 33554432               // commitment[16], then codebook[16]
#define OUT_OFF_IDX  33554464               // indices as float [65536]

// ---------------- k0: normalized codebook (+cq table) + w_in_t ---------------
__global__ __launch_bounds__(256) void k0_prep(const float* __restrict__ v_in,
                                               const float* __restrict__ g_in,
                                               const float* __restrict__ codebook,
                                               float* __restrict__ ws) {
    int bid = blockIdx.x, tid = threadIdx.x;
    if (bid < 4) {
        int e = bid * 256 + tid;
        const float* c = codebook + (size_t)e * 8;
        float v[8]; float s = 0.f;
#pragma unroll
        for (int j = 0; j < 8; ++j) { v[j] = c[j]; s += v[j] * v[j]; }
        float qn = sqrtf(s);
        float rn = 1.0f / fmaxf(qn, 1e-12f);
        float cs = 0.f;
        float* o = ws + WS_CBN + (size_t)e * 8;
#pragma unroll
        for (int j = 0; j < 8; ++j) { float cn = v[j] * rn; o[j] = cn; cs += cn * cn; }
        float* q = ws + WS_CQ + (size_t)e * 4;
        q[0] = cs; q[1] = qn; q[2] = s; q[3] = 0.f;
    } else {
        // w_in_t[i][o] = g_in[o] * v_in[o][i] / ||v_in[o,:]||
        __shared__ float part[8][33];
        __shared__ float rn[8];
        int o = tid >> 5;       // 0..7
        int g = tid & 31;       // 0..31
        float s = 0.f;
        for (int i = g * 16; i < g * 16 + 16; ++i) { float x = v_in[o * 512 + i]; s += x * x; }
        part[o][g] = s;
        __syncthreads();
        if (tid < 8) {
            float t2 = 0.f;
            for (int gg = 0; gg < 32; ++gg) t2 += part[tid][gg];
            rn[tid] = g_in[tid] / sqrtf(t2);
        }
        __syncthreads();
        for (int ii = 0; ii < 2; ++ii) {
            int i = tid * 2 + ii;
#pragma unroll
            for (int oo = 0; oo < 8; ++oo)
                ws[WS_WIN_T + i * 8 + oo] = v_in[oo * 512 + i] * rn[oo];
        }
    }
}

// ---------------- k0b: pcb[e][o] = b_out[o] + sum_j w_out[o][j]*cb[e][j] -----
__global__ __launch_bounds__(256) void k0b_pcb(const float* __restrict__ v_out,
                                               const float* __restrict__ g_out,
                                               const float* __restrict__ b_out,
                                               const float* __restrict__ codebook,
                                               float* __restrict__ ws_pcb) {
    int e = blockIdx.x, tid = threadIdx.x;
    const float4* cq = (const float4*)(codebook + (size_t)e * 8);
    float4 q0 = cq[0], q1 = cq[1];
    float2 res;
    float* rp = &res.x;
#pragma unroll
    for (int ii = 0; ii < 2; ++ii) {
        int o = tid * 2 + ii;
        const float4* vr = (const float4*)(v_out + (size_t)o * 8);
        float4 va = vr[0], vb = vr[1];
        float s = va.x * va.x + va.y * va.y + va.z * va.z + va.w * va.w
                + vb.x * vb.x + vb.y * vb.y + vb.z * vb.z + vb.w * vb.w;
        float rn = g_out[o] / sqrtf(s);
        float x = b_out[o];
        x = fmaf(va.x * rn, q0.x, x); x = fmaf(va.y * rn, q0.y, x);
        x = fmaf(va.z * rn, q0.z, x); x = fmaf(va.w * rn, q0.w, x);
        x = fmaf(vb.x * rn, q1.x, x); x = fmaf(vb.y * rn, q1.y, x);
        x = fmaf(vb.z * rn, q1.z, x); x = fmaf(vb.w * rn, q1.w, x);
        rp[ii] = x;
    }
    ((float2*)(ws_pcb + (size_t)e * 512))[tid] = res;
}

// ---------------- k1: in_proj partials over D-chunks (R2 geometry) -----------
// grid (256, 8): blockIdx.x = token block (256 tokens), blockIdx.y = D-chunk
// (64 rows). Each thread accumulates an 8-dim partial for one token.
__global__ __launch_bounds__(256) void k1_inproj(const float* __restrict__ z,
                                                 const float* __restrict__ ws_w,
                                                 float* __restrict__ ws_zep) {
    __shared__ float w[512];   // w_in_t chunk [64][8]
    int tid = threadIdx.x;
    int c = blockIdx.y;
    if (tid < 128)
        ((float4*)w)[tid] = ((const float4*)(ws_w + c * 512))[tid];
    __syncthreads();

    int tok = blockIdx.x * 256 + tid;
    int b = tok >> 12;
    int t = tok & (T_ - 1);

    float4 a0 = make_float4(0.f, 0.f, 0.f, 0.f);
    float4 a1 = make_float4(0.f, 0.f, 0.f, 0.f);

    const float* zp = z + (size_t)b * D_ * T_ + (size_t)(c * 64) * T_ + t;
#pragma unroll 8
    for (int i = 0; i < 64; ++i) {
        float v = zp[(size_t)i * T_];
        float4 wa = ((float4*)w)[i * 2];
        float4 wb = ((float4*)w)[i * 2 + 1];
        a0.x = fmaf(wa.x, v, a0.x); a0.y = fmaf(wa.y, v, a0.y);
        a0.z = fmaf(wa.z, v, a0.z); a0.w = fmaf(wa.w, v, a0.w);
        a1.x = fmaf(wb.x, v, a1.x); a1.y = fmaf(wb.y, v, a1.y);
        a1.z = fmaf(wb.z, v, a1.z); a1.w = fmaf(wb.w, v, a1.w);
    }
    float4* zo = (float4*)(ws_zep + ((size_t)c * NTOK_ + tok) * 8);
    zo[0] = a0; zo[1] = a1;
}

// ---------------- k2: partial-reduce + nearest-codebook search ---------------
// 1024 blocks x 128 threads (2 waves). Each wave holds the FULL codebook in
// registers (16 entries/lane) and scans 32 tokens broadcast from LDS.
// Winner's dot is reconstructed from the winning dist (no dotw carry).
__global__ __launch_bounds__(128) void k2_search(const float* __restrict__ ws,
                                                 const float* __restrict__ b_in,
                                                 float* __restrict__ out_idx_f,
                                                 int* __restrict__ ws_idx,
                                                 float* __restrict__ ws_bpart) {
    __shared__ float zes[64 * 8];     // 2 KB
    __shared__ float4 cqt[1024];      // 16 KB: cc, ||q||, ||q||^2
    __shared__ float wl[2];
    int tid = threadIdx.x;
    int lane = tid & 63;
    int wv = tid >> 6;

    int base = blockIdx.x * 64;
    // stage 64 tokens of z_e = sum of 8 chunk-partials + bias
    {
        float4 bia = ((const float4*)b_in)[tid & 1];
        const float4* zp = (const float4*)(ws + WS_ZEP);
        size_t o = (size_t)base * 2 + tid;
        float4 s = bia;
#pragma unroll
        for (int c = 0; c < 8; ++c) {
            float4 v = zp[(size_t)c * (NTOK_ * 2) + o];
            s.x += v.x; s.y += v.y; s.z += v.z; s.w += v.w;
        }
        ((float4*)zes)[tid] = s;
    }
    // stage cq table
    {
        const float4* src = (const float4*)(ws + WS_CQ);
#pragma unroll
        for (int k = 0; k < 8; ++k) cqt[tid + k * 128] = src[tid + k * 128];
    }

    // load 16 codebook entries per lane: e = k*64 + lane
    float cbn[16][8]; float cc[16];
    const float* cb = ws + WS_CBN;
#pragma unroll
    for (int k = 0; k < 16; ++k) {
        const float4* p = (const float4*)(cb + (size_t)(k * 64 + lane) * 8);
        float4 p0 = p[0], p1 = p[1];
        cbn[k][0] = p0.x; cbn[k][1] = p0.y; cbn[k][2] = p0.z; cbn[k][3] = p0.w;
        cbn[k][4] = p1.x; cbn[k][5] = p1.y; cbn[k][6] = p1.z; cbn[k][7] = p1.w;
        cc[k] = ws[WS_CQ + (size_t)(k * 64 + lane) * 4];
    }
    __syncthreads();

    float lossAcc = 0.f;
    for (int s = 0; s < 32; ++s) {
        int tl = wv * 32 + s;
        int tok = base + tl;
        float4 z0 = ((float4*)zes)[tl * 2];
        float4 z1 = ((float4*)zes)[tl * 2 + 1];
        float nrm2 = z0.x * z0.x + z0.y * z0.y + z0.z * z0.z + z0.w * z0.w
                   + z1.x * z1.x + z1.y * z1.y + z1.z * z1.z + z1.w * z1.w;
        float zen = fmaxf(sqrtf(nrm2), 1e-12f);
        float r = 1.0f / zen;
        float e0 = z0.x * r, e1 = z0.y * r, e2 = z0.z * r, e3 = z0.w * r;
        float e4 = z1.x * r, e5 = z1.y * r, e6 = z1.z * r, e7 = z1.w * r;
        float a = e0 * e0 + e1 * e1 + e2 * e2 + e3 * e3
                + e4 * e4 + e5 * e5 + e6 * e6 + e7 * e7;

        float best = 3.4e38f; int bidx = 0x7fffffff;
#pragma unroll
        for (int k = 0; k < 16; ++k) {
            float dot = cbn[k][0] * e0;
            dot = fmaf(cbn[k][1], e1, dot);
            dot = fmaf(cbn[k][2], e2, dot);
            dot = fmaf(cbn[k][3], e3, dot);
            dot = fmaf(cbn[k][4], e4, dot);
            dot = fmaf(cbn[k][5], e5, dot);
            dot = fmaf(cbn[k][6], e6, dot);
            dot = fmaf(cbn[k][7], e7, dot);
            float dist = fmaf(dot, -2.0f, a) + cc[k];   // (a - 2*dot) + c
            int e = k * 64 + lane;
            if (dist < best) { best = dist; bidx = e; }  // strict < -> first-min
        }
        // 64-lane lexicographic (dist, idx) min reduce -> all lanes converge
#pragma unroll
        for (int off = 1; off < 64; off <<= 1) {
            float ov = __shfl_xor(best, off, 64);
            int   oi = __shfl_xor(bidx, off, 64);
            if (ov < best || (ov == best && oi < bidx)) { best = ov; bidx = oi; }
        }
        // reconstruct dot from winning dist; loss = |z_e|^2 - 2*dot*|z_e|*|q| + |q|^2
        float4 q = cqt[bidx];
        float dot = (a + q.x - best) * 0.5f;
        lossAcc += nrm2 - 2.0f * dot * zen * q.y + q.z;

        if (lane == 0) {
            out_idx_f[tok] = (float)bidx;
            ws_idx[tok] = bidx;
        }
    }
    if (lane == 0) wl[wv] = lossAcc;
    __syncthreads();
    if (tid == 0) ws_bpart[blockIdx.x] = wl[0] + wl[1];
}

// ---------------- k3: gather-copy out_proj + loss finalize -------------------
// grid (256, 8): out[b, c*64+o, t] = pcb[idx[tok]][c*64+o]  (bias baked in).
__global__ __launch_bounds__(256) void k3_gather(const float* __restrict__ ws,
                                                 const int* __restrict__ ws_idx,
                                                 const float* __restrict__ ws_bpart,
                                                 float* __restrict__ d_out) {
    int tid = threadIdx.x;
    int c = blockIdx.y;
    int tok = blockIdx.x * 256 + tid;
    int b = tok >> 12;
    int t = tok & (T_ - 1);
    int idx = ws_idx[tok];

    const float4* prow = (const float4*)(ws + WS_PCB + (size_t)idx * 512 + c * 64);
    float* op = d_out + (size_t)b * D_ * T_ + (size_t)(c * 64) * T_ + t;
#pragma unroll
    for (int k = 0; k < 16; ++k) {
        float4 v = prow[k];
        op[(size_t)(k * 4 + 0) * T_] = v.x;
        op[(size_t)(k * 4 + 1) * T_] = v.y;
        op[(size_t)(k * 4 + 2) * T_] = v.z;
        op[(size_t)(k * 4 + 3) * T_] = v.w;
    }

    if (blockIdx.x == 0 && c == 0 && tid < B_) {
        float s = 0.f;
        for (int k = 0; k < 64; ++k) s += ws_bpart[tid * 64 + k];
        float m = s * (1.0f / (CD_ * T_));
        d_out[OUT_OFF_LOSS + tid] = m;
        d_out[OUT_OFF_LOSS + 16 + tid] = m;
    }
}

// ---------------- launch -----------------------------------------------------
extern "C" void kernel_launch(void* const* d_in, const int* in_sizes, int n_in,
                              void* d_out, int out_size, void* d_ws, size_t ws_size,
                              hipStream_t stream) {
    (void)in_sizes; (void)n_in; (void)out_size; (void)ws_size;
    const float* z        = (const float*)d_in[0];
    const float* v_in     = (const float*)d_in[1];
    const float* g_in     = (const float*)d_in[2];
    const float* b_in     = (const float*)d_in[3];
    const float* v_out    = (const float*)d_in[4];
    const float* g_out    = (const float*)d_in[5];
    const float* b_out    = (const float*)d_in[6];
    const float* codebook = (const float*)d_in[7];
    float* ws  = (float*)d_ws;
    float* out = (float*)d_out;

    hipLaunchKernelGGL(k0_prep, dim3(5), dim3(256), 0, stream,
                       v_in, g_in, codebook, ws);
    hipLaunchKernelGGL(k0b_pcb, dim3(CBN_), dim3(256), 0, stream,
                       v_out, g_out, b_out, codebook, ws + WS_PCB);
    hipLaunchKernelGGL(k1_inproj, dim3(NTOK_ / 256, 8), dim3(256), 0, stream,
                       z, ws + WS_WIN_T, ws + WS_ZEP);
    hipLaunchKernelGGL(k2_search, dim3(NTOK_ / 64), dim3(128), 0, stream,
                       ws, b_in, out + OUT_OFF_IDX,
                       (int*)(ws + WS_IDX), ws + WS_BPART);
    hipLaunchKernelGGL(k3_gather, dim3(NTOK_ / 256, 8), dim3(256), 0, stream,
                       ws, (const int*)(ws + WS_IDX), ws + WS_BPART, out);
}

// Round 6
// 98.191 us; speedup vs baseline: 1.1957x; 1.1957x over previous
//
#include <hip/hip_runtime.h>
#include <math.h>

#define B_    16
#define D_    512
#define T_    4096
#define CBN_  1024
#define CD_   8
#define NTOK_ (B_ * T_)   // 65536

#define WS_BPART 0                          // ws float offsets: bpart[1024]

#define OUT_OFF_LOSS 33554432               // commitment[16], then codebook[16]
#define OUT_OFF_IDX  33554464               // indices as float [65536]

// ============ fused: in_proj + search + loss-partial + out_proj ==============
// grid 1024 x 128 threads (2 waves). Block = 64 tokens (blk>>6 = batch,
// (blk&63)*64 = t base). Phases:
//  ph0: w_in weight-norm -> LDS; ph1: 2-way K-split in_proj (z read once);
//  ph2: finalize z_e + normalize (wave0); ph3: R2-style register-codebook
//  search (16 entries/lane/wave, full codebook per wave, 32 tokens each),
//  loss via dist-reconstruction; ph4: w_out weight-norm -> LDS (reuse);
//  ph5: out = w_out @ codebook[idx] + b_out, coalesced stores.
__global__ __launch_bounds__(128) void vq_fused(const float* __restrict__ z,
                                                const float* __restrict__ v_in,
                                                const float* __restrict__ g_in,
                                                const float* __restrict__ b_in,
                                                const float* __restrict__ v_out,
                                                const float* __restrict__ g_out,
                                                const float* __restrict__ b_out,
                                                const float* __restrict__ codebook,
                                                float* __restrict__ d_out,
                                                float* __restrict__ bpart) {
    __shared__ float wlds[512 * 8];     // 16 KB: w_in_t [i][o], later w_out [o][j]
    __shared__ float part[2 * 64 * 9];  // 4.5 KB: per-wave z_e partials, stride 9
    __shared__ float enorm[64 * 12];    // 3 KB: e[8], a, nrm2, zen, pad
    __shared__ float bo[512];           // 2 KB
    __shared__ float pnorm[8 * 17];     // w_in col-norm partials
    __shared__ float rn8[8];
    __shared__ int   idxl[64];
    __shared__ float wl[2];

    int tid = threadIdx.x;
    int wv = tid >> 6;
    int l  = tid & 63;
    int blk = blockIdx.x;
    int b = blk >> 6;
    int tb = (blk & 63) << 6;

    // ---- ph0: w_in_t[i][o] = g_in[o] * v_in[o][i] / ||v_in[o,:]|| ----
    {
        int o = tid >> 4, g = tid & 15;
        float s = 0.f;
        for (int i = g * 32; i < g * 32 + 32; ++i) { float x = v_in[o * 512 + i]; s += x * x; }
        pnorm[o * 17 + g] = s;
    }
    __syncthreads();
    if (tid < 8) {
        float t2 = 0.f;
        for (int gg = 0; gg < 16; ++gg) t2 += pnorm[tid * 17 + gg];
        rn8[tid] = g_in[tid] / sqrtf(t2);
    }
    __syncthreads();
    for (int ii = 0; ii < 4; ++ii) {
        int i = tid * 4 + ii;
#pragma unroll
        for (int o = 0; o < 8; ++o) wlds[i * 8 + o] = v_in[o * 512 + i] * rn8[o];
    }
    __syncthreads();

    // ---- ph1: in_proj partial; wave wv covers rows [wv*256, wv*256+256) ----
    {
        float acc[8];
#pragma unroll
        for (int j = 0; j < 8; ++j) acc[j] = 0.f;
        const float* zp = z + (size_t)b * D_ * T_ + (size_t)(wv * 256) * T_ + tb + l;
        const float4* wp = ((const float4*)wlds) + wv * 512;
#pragma unroll 8
        for (int i = 0; i < 256; ++i) {
            float v = zp[(size_t)i * T_];
            float4 wa = wp[i * 2];
            float4 wb = wp[i * 2 + 1];
            acc[0] = fmaf(wa.x, v, acc[0]); acc[1] = fmaf(wa.y, v, acc[1]);
            acc[2] = fmaf(wa.z, v, acc[2]); acc[3] = fmaf(wa.w, v, acc[3]);
            acc[4] = fmaf(wb.x, v, acc[4]); acc[5] = fmaf(wb.y, v, acc[5]);
            acc[6] = fmaf(wb.z, v, acc[6]); acc[7] = fmaf(wb.w, v, acc[7]);
        }
        float* pp = &part[(wv * 64 + l) * 9];
#pragma unroll
        for (int j = 0; j < 8; ++j) pp[j] = acc[j];
    }
    __syncthreads();

    // ---- ph2: wave0 finalizes z_e, normalizes, stages to enorm ----
    if (wv == 0) {
        float ze[8];
#pragma unroll
        for (int j = 0; j < 8; ++j)
            ze[j] = b_in[j] + part[l * 9 + j] + part[(64 + l) * 9 + j];
        float nrm2 = ze[0] * ze[0] + ze[1] * ze[1] + ze[2] * ze[2] + ze[3] * ze[3]
                   + ze[4] * ze[4] + ze[5] * ze[5] + ze[6] * ze[6] + ze[7] * ze[7];
        float zen = fmaxf(sqrtf(nrm2), 1e-12f);
        float r = 1.0f / zen;
        float e0 = ze[0] * r, e1 = ze[1] * r, e2 = ze[2] * r, e3 = ze[3] * r;
        float e4 = ze[4] * r, e5 = ze[5] * r, e6 = ze[6] * r, e7 = ze[7] * r;
        float a = e0 * e0 + e1 * e1 + e2 * e2 + e3 * e3
                + e4 * e4 + e5 * e5 + e6 * e6 + e7 * e7;
        float* ep = &enorm[l * 12];
        ep[0] = e0; ep[1] = e1; ep[2] = e2; ep[3] = e3;
        ep[4] = e4; ep[5] = e5; ep[6] = e6; ep[7] = e7;
        ep[8] = a; ep[9] = nrm2; ep[10] = zen; ep[11] = 0.f;
    }
    __syncthreads();

    // ---- codebook into registers: 16 entries/lane (e = k*64 + lane), both waves ----
    float cbn[16][8]; float cc[16];
#pragma unroll
    for (int k = 0; k < 16; ++k) {
        const float* cp = codebook + (size_t)(k * 64 + l) * 8;
        float v[8]; float s = 0.f;
#pragma unroll
        for (int j = 0; j < 8; ++j) { v[j] = cp[j]; s += v[j] * v[j]; }
        float rn = 1.0f / fmaxf(sqrtf(s), 1e-12f);
        float cs = 0.f;
#pragma unroll
        for (int j = 0; j < 8; ++j) { float cn = v[j] * rn; cbn[k][j] = cn; cs += cn * cn; }
        cc[k] = cs;
    }

    // ---- ph3: search; wave wv scans tokens [wv*32, wv*32+32) ----
    float lossAcc = 0.f;
    for (int s = 0; s < 32; ++s) {
        int tl = wv * 32 + s;
        float4 E0 = ((float4*)enorm)[tl * 3 + 0];
        float4 E1 = ((float4*)enorm)[tl * 3 + 1];
        float4 E2 = ((float4*)enorm)[tl * 3 + 2];   // a, nrm2, zen
        float e0 = E0.x, e1 = E0.y, e2 = E0.z, e3 = E0.w;
        float e4 = E1.x, e5 = E1.y, e6 = E1.z, e7 = E1.w;
        float a = E2.x, nrm2 = E2.y, zen = E2.z;

        float best = 3.4e38f; int bidx = 0x7fffffff;
#pragma unroll
        for (int k = 0; k < 16; ++k) {
            float dot = cbn[k][0] * e0;
            dot = fmaf(cbn[k][1], e1, dot);
            dot = fmaf(cbn[k][2], e2, dot);
            dot = fmaf(cbn[k][3], e3, dot);
            dot = fmaf(cbn[k][4], e4, dot);
            dot = fmaf(cbn[k][5], e5, dot);
            dot = fmaf(cbn[k][6], e6, dot);
            dot = fmaf(cbn[k][7], e7, dot);
            float dist = fmaf(dot, -2.0f, a) + cc[k];   // (a - 2*dot) + c
            int e = k * 64 + l;
            if (dist < best) { best = dist; bidx = e; }  // strict < -> first-min
        }
#pragma unroll
        for (int off = 1; off < 64; off <<= 1) {
            float ov = __shfl_xor(best, off, 64);
            int   oi = __shfl_xor(bidx, off, 64);
            if (ov < best || (ov == best && oi < bidx)) { best = ov; bidx = oi; }
        }
        // loss via reconstruction: dot=(a+cc-best)/2; loss=nrm2-2*dot*|ze|*|q|+|q|^2
        {
            const float* cq = codebook + (size_t)bidx * 8;
            float v[8]; float sw = 0.f;
#pragma unroll
            for (int j = 0; j < 8; ++j) { v[j] = cq[j]; sw += v[j] * v[j]; }
            float qn = sqrtf(sw);
            float rnq = 1.0f / fmaxf(qn, 1e-12f);
            float cs = 0.f;
#pragma unroll
            for (int j = 0; j < 8; ++j) { float cn = v[j] * rnq; cs += cn * cn; }
            float dot = (a + cs - best) * 0.5f;
            lossAcc += nrm2 - 2.0f * dot * zen * qn + sw;
        }
        if (l == 0) {
            int tok = blk * 64 + tl;
            d_out[OUT_OFF_IDX + tok] = (float)bidx;
            idxl[tl] = bidx;
        }
    }
    if (l == 0) wl[wv] = lossAcc;
    __syncthreads();
    if (tid == 0) bpart[blk] = wl[0] + wl[1];

    // ---- ph4: w_out (weight-normed) + bias into LDS (reuse wlds) ----
    for (int ii = 0; ii < 4; ++ii) {
        int o = tid * 4 + ii;
        const float4* vr = (const float4*)(v_out + (size_t)o * 8);
        float4 va = vr[0], vb = vr[1];
        float s = va.x * va.x + va.y * va.y + va.z * va.z + va.w * va.w
                + vb.x * vb.x + vb.y * vb.y + vb.z * vb.z + vb.w * vb.w;
        float rn = g_out[o] / sqrtf(s);
        float* wo = &wlds[o * 8];
        wo[0] = va.x * rn; wo[1] = va.y * rn; wo[2] = va.z * rn; wo[3] = va.w * rn;
        wo[4] = vb.x * rn; wo[5] = vb.y * rn; wo[6] = vb.z * rn; wo[7] = vb.w * rn;
        bo[o] = b_out[o];
    }
    __syncthreads();

    // ---- ph5: out; lane l <-> token, wave wv covers rows [wv*256, +256) ----
    {
        int idx = idxl[l];
        const float4* cq4 = (const float4*)(codebook + (size_t)idx * 8);
        float4 q0 = cq4[0], q1 = cq4[1];
        float* op = d_out + (size_t)b * D_ * T_ + tb + l;
#pragma unroll 8
        for (int oi = 0; oi < 256; ++oi) {
            int o = wv * 256 + oi;
            float4 wa = ((float4*)wlds)[o * 2];
            float4 wb = ((float4*)wlds)[o * 2 + 1];
            float x = bo[o];
            x = fmaf(wa.x, q0.x, x); x = fmaf(wa.y, q0.y, x);
            x = fmaf(wa.z, q0.z, x); x = fmaf(wa.w, q0.w, x);
            x = fmaf(wb.x, q1.x, x); x = fmaf(wb.y, q1.y, x);
            x = fmaf(wb.z, q1.z, x); x = fmaf(wb.w, q1.w, x);
            op[(size_t)o * T_] = x;
        }
    }
}

// ============ finalize: per-batch loss reduction =============================
__global__ __launch_bounds__(64) void vq_finalize(const float* __restrict__ bpart,
                                                  float* __restrict__ d_out) {
    int tid = threadIdx.x;
    if (tid < B_) {
        float s = 0.f;
        for (int k = 0; k < 64; ++k) s += bpart[tid * 64 + k];
        float m = s * (1.0f / (CD_ * T_));
        d_out[OUT_OFF_LOSS + tid] = m;
        d_out[OUT_OFF_LOSS + 16 + tid] = m;
    }
}

// ---------------- launch -----------------------------------------------------
extern "C" void kernel_launch(void* const* d_in, const int* in_sizes, int n_in,
                              void* d_out, int out_size, void* d_ws, size_t ws_size,
                              hipStream_t stream) {
    (void)in_sizes; (void)n_in; (void)out_size; (void)ws_size;
    const float* z        = (const float*)d_in[0];
    const float* v_in     = (const float*)d_in[1];
    const float* g_in     = (const float*)d_in[2];
    const float* b_in     = (const float*)d_in[3];
    const float* v_out    = (const float*)d_in[4];
    const float* g_out    = (const float*)d_in[5];
    const float* b_out    = (const float*)d_in[6];
    const float* codebook = (const float*)d_in[7];
    float* ws  = (float*)d_ws;
    float* out = (float*)d_out;

    hipLaunchKernelGGL(vq_fused, dim3(NTOK_ / 64), dim3(128), 0, stream,
                       z, v_in, g_in, b_in, v_out, g_out, b_out, codebook,
                       out, ws + WS_BPART);
    hipLaunchKernelGGL(vq_finalize, dim3(1), dim3(64), 0, stream,
                       ws + WS_BPART, out);
}